// Round 15
// baseline (43.947 us; speedup 1.0000x reference)
//
#include <hip/hip_runtime.h>
#include <hip/hip_fp16.h>

#define LN2D 0.6931471805599453094172321

typedef float v2f __attribute__((ext_vector_type(2)));

// lane l gets lane l-1's v; lane 0 gets fill. VALU DPP, no LDS.
__device__ __forceinline__ float shr1(float v, float fill) {
    return __int_as_float(__builtin_amdgcn_update_dpp(
        __float_as_int(fill), __float_as_int(v), 0x138 /*wave_shr:1*/, 0xF, 0xF, false));
}
// lane l gets lane l+1's v; lane 63 gets fill.
__device__ __forceinline__ float shl1(float v, float fill) {
    return __int_as_float(__builtin_amdgcn_update_dpp(
        __float_as_int(fill), __float_as_int(v), 0x130 /*wave_shl:1*/, 0xF, 0xF, false));
}

// DPP wave64 reduce (row_shr 1,2,4,8; bcast15; bcast31) -> valid in lane 63.
__device__ __forceinline__ float wave_sum63(float x) {
    int t;
    t = __builtin_amdgcn_update_dpp(0, __float_as_int(x), 0x111, 0xF, 0xF, true);
    x += __int_as_float(t);
    t = __builtin_amdgcn_update_dpp(0, __float_as_int(x), 0x112, 0xF, 0xF, true);
    x += __int_as_float(t);
    t = __builtin_amdgcn_update_dpp(0, __float_as_int(x), 0x114, 0xF, 0xF, true);
    x += __int_as_float(t);
    t = __builtin_amdgcn_update_dpp(0, __float_as_int(x), 0x118, 0xF, 0xF, true);
    x += __int_as_float(t);
    t = __builtin_amdgcn_update_dpp(0, __float_as_int(x), 0x142, 0xA, 0xF, true);
    x += __int_as_float(t);
    t = __builtin_amdgcn_update_dpp(0, __float_as_int(x), 0x143, 0xC, 0xF, true);
    x += __int_as_float(t);
    return x;
}

__device__ __forceinline__ float wave_max63(float x) {
    int iv = __float_as_int(x); int t;
    t = __builtin_amdgcn_update_dpp(iv, iv, 0x111, 0xF, 0xF, false);
    x = fmaxf(x, __int_as_float(t)); iv = __float_as_int(x);
    t = __builtin_amdgcn_update_dpp(iv, iv, 0x112, 0xF, 0xF, false);
    x = fmaxf(x, __int_as_float(t)); iv = __float_as_int(x);
    t = __builtin_amdgcn_update_dpp(iv, iv, 0x114, 0xF, 0xF, false);
    x = fmaxf(x, __int_as_float(t)); iv = __float_as_int(x);
    t = __builtin_amdgcn_update_dpp(iv, iv, 0x118, 0xF, 0xF, false);
    x = fmaxf(x, __int_as_float(t)); iv = __float_as_int(x);
    t = __builtin_amdgcn_update_dpp(iv, iv, 0x142, 0xA, 0xF, false);
    x = fmaxf(x, __int_as_float(t)); iv = __float_as_int(x);
    t = __builtin_amdgcn_update_dpp(iv, iv, 0x143, 0xC, 0xF, false);
    x = fmaxf(x, __int_as_float(t));
    return x;
}

__device__ __forceinline__ float rdl63(float v) {
    return __int_as_float(__builtin_amdgcn_readlane(__float_as_int(v), 63));
}

#define VSTRIDE 260

// One block per (batch, half): 4 waves produce this half's 256 rows of the
// emission stream into LDS (batched asm loads, counted vmcnt(8) dbuf so 16
// loads stay in flight); then wave 0 runs the 256-step half-chain (h=0 fwd
// from t=0, h=1 bwd from t=511) and publishes the t=255 boundary vector.
__global__ __launch_bounds__(256) void ctc_half(const int* __restrict__ yt,
                                                const float* __restrict__ yp,
                                                float* __restrict__ V,
                                                int* __restrict__ E,
                                                float* __restrict__ accW) {
    constexpr int L = 128;
    const int bh   = blockIdx.x;          // b*2 + h
    const int b    = bh >> 1, h = bh & 1;
    const int w    = threadIdx.x >> 6;
    const int lane = threadIdx.x & 63;

    __shared__ int g[256][64];            // 64 KB: half2(d1,d3) bits per (row,lane)

    const int2 cc = *reinterpret_cast<const int2*>(yt + b * L + 2 * lane);
    const int c1 = cc.x, c3 = cc.y;
    const int sl1 = c1 >> 1, sh1v = (c1 & 1) << 4;
    const int sl3 = c3 >> 1, sh3v = (c3 & 1) << 4;

    // ---------------- produce: 64 rows per wave ----------------
    float acc = 0.0f;
    const float* src = yp + ((size_t)b * 512 + h * 256 + w * 64) * 128 + lane * 2;
    v2f A8[8], B8[8];

#define ISSUE8(d_, p_)                                                         \
    asm volatile(                                                              \
        "global_load_dwordx2 %0, %8, off\n\t"                                  \
        "global_load_dwordx2 %1, %8, off offset:512\n\t"                       \
        "global_load_dwordx2 %2, %8, off offset:1024\n\t"                      \
        "global_load_dwordx2 %3, %8, off offset:1536\n\t"                      \
        "global_load_dwordx2 %4, %8, off offset:2048\n\t"                      \
        "global_load_dwordx2 %5, %8, off offset:2560\n\t"                      \
        "global_load_dwordx2 %6, %8, off offset:3072\n\t"                      \
        "global_load_dwordx2 %7, %8, off offset:3584"                          \
        : "=&v"(d_[0]), "=&v"(d_[1]), "=&v"(d_[2]), "=&v"(d_[3]),              \
          "=&v"(d_[4]), "=&v"(d_[5]), "=&v"(d_[6]), "=&v"(d_[7])               \
        : "v"(p_)                                                              \
        : "memory");

#define WAITN(n_)                                                              \
    {                                                                          \
        asm volatile("s_waitcnt vmcnt(" #n_ ")" ::: "memory");                 \
        __builtin_amdgcn_sched_barrier(0);                                     \
    }

#define PROC8(buf_, rb_)                                                       \
    {                                                                          \
        _Pragma("unroll")                                                      \
        for (int i = 0; i < 8; ++i) {                                          \
            const float vx = buf_[i].x, vy = buf_[i].y;                        \
            const float sall = rdl63(wave_sum63(__expf(vx) + __expf(vy)));     \
            const float xbv  = rdl63(vy);     /* blank = lane63.y */           \
            acc += __logf(sall) - xbv;                                         \
            const __half2 hh = __floats2half2_rn(vx, vy);                      \
            const int hb = __builtin_bit_cast(int, hh);                        \
            const int q1 = __shfl(hb, sl1, 64);                                \
            const int q3 = __shfl(hb, sl3, 64);                                \
            const float x1 = __half2float(__builtin_bit_cast(__half, (unsigned short)(q1 >> sh1v))); \
            const float x3 = __half2float(__builtin_bit_cast(__half, (unsigned short)(q3 >> sh3v))); \
            g[w * 64 + (rb_) + i][lane] =                                      \
                __builtin_bit_cast(int, __floats2half2_rn(x1 - xbv, x3 - xbv)); \
        }                                                                      \
    }

    ISSUE8(A8, src)
    ISSUE8(B8, src + 8 * 128)
    WAITN(8)  PROC8(A8, 0)   ISSUE8(A8, src + 16 * 128)
    WAITN(8)  PROC8(B8, 8)   ISSUE8(B8, src + 24 * 128)
    WAITN(8)  PROC8(A8, 16)  ISSUE8(A8, src + 32 * 128)
    WAITN(8)  PROC8(B8, 24)  ISSUE8(B8, src + 40 * 128)
    WAITN(8)  PROC8(A8, 32)  ISSUE8(A8, src + 48 * 128)
    WAITN(8)  PROC8(B8, 40)  ISSUE8(B8, src + 56 * 128)
    WAITN(8)  PROC8(A8, 48)
    WAITN(0)  PROC8(B8, 56)

    if (lane == 0) accW[bh * 4 + w] = acc;
    __syncthreads();

    // ---------------- chain: wave 0 only ----------------
    if (w == 0) {
        const int cprev = __shfl_up(c3, 1, 64);
        const float sk1 = (lane > 0 && c1 != cprev) ? 1.0f : 0.0f;
        const float sk3 = (c3 != c1) ? 1.0f : 0.0f;
        const float skB3 = shl1(sk1, 0.0f);
        const int llen = __popcll(__ballot(c1 != 0)) + __popcll(__ballot(c3 != 0));

        float o0, o1, o2, o3, o4;
        int   Eacc = 0;

#define RENORM()                                                               \
    {                                                                          \
        float mr = fmaxf(fmaxf(fmaxf(o0, o1), fmaxf(o2, o3)), o4);             \
        const float mru = rdl63(wave_max63(mr));                               \
        const int ie = (__float_as_int(mru) >> 23) & 0xFF;                     \
        const float sc = __int_as_float((253 - ie) << 23);                     \
        o0 *= sc; o1 *= sc; o2 *= sc; o3 *= sc; o4 *= sc;                      \
        Eacc += ie - 126;                                                      \
    }

#define FSTEP(bits_, rn_)                                                      \
    {                                                                          \
        const float2 dd = __half22float2(__builtin_bit_cast(__half2, (bits_)));\
        const float e1 = __expf(dd.x);                                         \
        const float e3 = __expf(dd.y);                                         \
        const float pm = shr1(o3, 0.0f);                                       \
        const float n0 = o0 + pm;                                              \
        const float n1 = (o1 + o0 + sk1 * pm) * e1;                            \
        const float n2 = o2 + o1;                                              \
        const float n3 = (o3 + o2 + sk3 * o1) * e3;                            \
        o4 += o3;                                                              \
        o0 = n0; o1 = n1; o2 = n2; o3 = n3;                                    \
        if (rn_) RENORM();                                                     \
    }

#define BSTEP(bits_, rn_)                                                      \
    {                                                                          \
        const float2 dd = __half22float2(__builtin_bit_cast(__half2, (bits_)));\
        const float g1 = o1 * __expf(dd.x);                                    \
        const float g3 = o3 * __expf(dd.y);                                    \
        const float pm0 = shl1(o0, o4);      /* beta(4l+4); lane63 -> o4 */    \
        const float pm1 = shl1(g1, 0.0f);    /* gamma(4l+5); lane63 -> 0 */    \
        const float n0 = o0 + g1;                                              \
        const float n1 = g1 + o2 + sk3 * g3;                                   \
        const float n2 = o2 + g3;                                              \
        const float n3 = g3 + pm0 + skB3 * pm1;                                \
        o0 = n0; o1 = n1; o2 = n2; o3 = n3;                                    \
        if (rn_) RENORM();                                                     \
    }

        if (h == 0) {
            // forward: local rows 0..255 are global t = 0..255
            {
                const float2 d0 = __half22float2(__builtin_bit_cast(__half2, g[0][lane]));
                o0 = (lane == 0) ? 1.0f : 0.0f;
                o1 = (lane == 0) ? __expf(d0.x) : 0.0f;
                o2 = 0.0f; o3 = 0.0f; o4 = 0.0f;
            }
            #pragma unroll
            for (int t = 1; t < 32; ++t) FSTEP(g[t][lane], false);
            for (int tb = 32; tb < 256; tb += 32) {
                #pragma unroll
                for (int j = 0; j < 32; ++j) FSTEP(g[tb + j][lane], (j == 0));
            }
        } else {
            // backward: local rows 0..255 are global t = 256..511; walk down.
            const int sA = 2 * llen, sB = 2 * llen - 1;   // readout states
            o0 = (4 * lane + 0 == sA) ? 1.0f : 0.0f;
            o1 = (4 * lane + 1 == sB) ? 1.0f : 0.0f;
            o2 = (4 * lane + 2 == sA) ? 1.0f : 0.0f;
            o3 = (4 * lane + 3 == sB) ? 1.0f : 0.0f;
            o4 = (llen == 128 && lane == 63) ? 1.0f : 0.0f;   // s = 256
            for (int sb = 0; sb < 256; sb += 32) {
                #pragma unroll
                for (int u = 1; u <= 32; ++u) BSTEP(g[256 - (sb + u)][lane], (u == 32));
            }
        }

        // publish boundary vector (t = 255) + exponent
        float* Vh = V + (size_t)bh * VSTRIDE;
        Vh[4 * lane + 0] = o0; Vh[4 * lane + 1] = o1;
        Vh[4 * lane + 2] = o2; Vh[4 * lane + 3] = o3;
        if (lane == 63) Vh[256] = o4;
        if (lane == 0)  E[bh] = Eacc;
#undef BSTEP
#undef FSTEP
#undef RENORM
    }
#undef PROC8
#undef WAITN
#undef ISSUE8
}

// Combine: P = sum_s alphaF(s)*betaB(s) in DOUBLE (fp32 product of two
// max-normalized fields underflows when argmax states misalign).
__global__ __launch_bounds__(64) void combine(const float* __restrict__ V,
                                              const int* __restrict__ E,
                                              const float* __restrict__ accW,
                                              float* __restrict__ loss) {
    const int b = blockIdx.x, lane = threadIdx.x;
    const float* Vf = V + (size_t)(2 * b) * VSTRIDE;
    const float* Vb = Vf + VSTRIDE;
    const float4 a = *reinterpret_cast<const float4*>(Vf + 4 * lane);
    const float4 c = *reinterpret_cast<const float4*>(Vb + 4 * lane);
    double p = (double)a.x * (double)c.x + (double)a.y * (double)c.y
             + (double)a.z * (double)c.z + (double)a.w * (double)c.w;
    if (lane == 63) p += (double)Vf[256] * (double)Vb[256];
    #pragma unroll
    for (int off = 32; off > 0; off >>= 1) p += __shfl_xor(p, off, 64);
    if (lane == 0) {
        float ls = 0.0f;
        #pragma unroll
        for (int j = 0; j < 8; ++j) ls += accW[8 * b + j];
        const double lg = log(p) + (double)(E[2 * b] + E[2 * b + 1]) * LN2D - (double)ls;
        loss[b] = -(float)lg;
    }
}

// Deterministic mean over B=256 losses
__global__ __launch_bounds__(256) void finalize(const float* __restrict__ loss,
                                                float* __restrict__ out) {
    __shared__ float red[256];
    const int tid = threadIdx.x;
    red[tid] = loss[tid];
    __syncthreads();
    for (int off = 128; off > 0; off >>= 1) {
        if (tid < off) red[tid] += red[tid + off];
        __syncthreads();
    }
    if (tid == 0) out[0] = red[0] * (1.0f / 256.0f);
}

extern "C" void kernel_launch(void* const* d_in, const int* in_sizes, int n_in,
                              void* d_out, int out_size, void* d_ws, size_t ws_size,
                              hipStream_t stream) {
    constexpr int B = 256;
    const int*   y_true = (const int*)d_in[0];
    const float* y_pred = (const float*)d_in[1];
    float* out = (float*)d_out;

    float* V    = (float*)d_ws;                       // 512 * 260 floats
    int*   E    = (int*)(V + 512 * VSTRIDE);          // 512 ints
    float* accW = (float*)(E + 512);                  // 512 * 4 floats
    float* loss = accW + 2048;                        // 256 floats

    ctc_half<<<B * 2, 256, 0, stream>>>(y_true, y_pred, V, E, accW);
    combine<<<B, 64, 0, stream>>>(V, E, accW, loss);
    finalize<<<1, 256, 0, stream>>>(loss, out);
}

// Round 16
// 40.711 us; speedup vs baseline: 1.0795x; 1.0795x over previous
//
#include <hip/hip_runtime.h>
#include <hip/hip_fp16.h>

#define LN2D 0.6931471805599453094172321

typedef float v2f __attribute__((ext_vector_type(2)));

// lane l gets lane l-1's v; lane 0 gets fill. VALU DPP, no LDS.
__device__ __forceinline__ float shr1(float v, float fill) {
    return __int_as_float(__builtin_amdgcn_update_dpp(
        __float_as_int(fill), __float_as_int(v), 0x138 /*wave_shr:1*/, 0xF, 0xF, false));
}
// lane l gets lane l+1's v; lane 63 gets fill.
__device__ __forceinline__ float shl1(float v, float fill) {
    return __int_as_float(__builtin_amdgcn_update_dpp(
        __float_as_int(fill), __float_as_int(v), 0x130 /*wave_shl:1*/, 0xF, 0xF, false));
}

// DPP wave64 reduce (row_shr 1,2,4,8; bcast15; bcast31) -> valid in lane 63.
__device__ __forceinline__ float wave_sum63(float x) {
    int t;
    t = __builtin_amdgcn_update_dpp(0, __float_as_int(x), 0x111, 0xF, 0xF, true);
    x += __int_as_float(t);
    t = __builtin_amdgcn_update_dpp(0, __float_as_int(x), 0x112, 0xF, 0xF, true);
    x += __int_as_float(t);
    t = __builtin_amdgcn_update_dpp(0, __float_as_int(x), 0x114, 0xF, 0xF, true);
    x += __int_as_float(t);
    t = __builtin_amdgcn_update_dpp(0, __float_as_int(x), 0x118, 0xF, 0xF, true);
    x += __int_as_float(t);
    t = __builtin_amdgcn_update_dpp(0, __float_as_int(x), 0x142, 0xA, 0xF, true);
    x += __int_as_float(t);
    t = __builtin_amdgcn_update_dpp(0, __float_as_int(x), 0x143, 0xC, 0xF, true);
    x += __int_as_float(t);
    return x;
}

__device__ __forceinline__ float wave_max63(float x) {
    int iv = __float_as_int(x); int t;
    t = __builtin_amdgcn_update_dpp(iv, iv, 0x111, 0xF, 0xF, false);
    x = fmaxf(x, __int_as_float(t)); iv = __float_as_int(x);
    t = __builtin_amdgcn_update_dpp(iv, iv, 0x112, 0xF, 0xF, false);
    x = fmaxf(x, __int_as_float(t)); iv = __float_as_int(x);
    t = __builtin_amdgcn_update_dpp(iv, iv, 0x114, 0xF, 0xF, false);
    x = fmaxf(x, __int_as_float(t)); iv = __float_as_int(x);
    t = __builtin_amdgcn_update_dpp(iv, iv, 0x118, 0xF, 0xF, false);
    x = fmaxf(x, __int_as_float(t)); iv = __float_as_int(x);
    t = __builtin_amdgcn_update_dpp(iv, iv, 0x142, 0xA, 0xF, false);
    x = fmaxf(x, __int_as_float(t)); iv = __float_as_int(x);
    t = __builtin_amdgcn_update_dpp(iv, iv, 0x143, 0xC, 0xF, false);
    x = fmaxf(x, __int_as_float(t));
    return x;
}

__device__ __forceinline__ float rdl63(float v) {
    return __int_as_float(__builtin_amdgcn_readlane(__float_as_int(v), 63));
}

// pack two f32 as bf16 pair (round-to-nearest-even): lo = a, hi = b
__device__ __forceinline__ int pk_bf16(float a, float b) {
    unsigned ua = __float_as_uint(a), ub = __float_as_uint(b);
    ua = (ua + 0x7FFFu + ((ua >> 16) & 1u)) >> 16;
    ub = (ub + 0x7FFFu + ((ub >> 16) & 1u)) & 0xFFFF0000u;
    return (int)(ua | ub);
}

#define VSTRIDE 260

// One block per (batch, half): 4 waves produce this half's 256 rows of
// PRE-EXPONENTIATED emissions e1=exp(x[c1]-xb), e3=exp(x[c3]-xb) (bf16 pair)
// into LDS; wave 0 then runs the 256-step half-chain reading LDS through an
// 8-deep static-index register ring (no transcendentals on the chain).
__global__ __launch_bounds__(256) void ctc_half(const int* __restrict__ yt,
                                                const float* __restrict__ yp,
                                                float* __restrict__ V,
                                                int* __restrict__ E,
                                                float* __restrict__ accW) {
    constexpr int L = 128;
    const int bh   = blockIdx.x;          // b*2 + h
    const int b    = bh >> 1, h = bh & 1;
    const int w    = threadIdx.x >> 6;
    const int lane = threadIdx.x & 63;

    __shared__ int g[256][64];            // 64 KB: bf16(e1)|bf16(e3)<<16

    const int2 cc = *reinterpret_cast<const int2*>(yt + b * L + 2 * lane);
    const int c1 = cc.x, c3 = cc.y;
    const int sl1 = c1 >> 1, sh1v = (c1 & 1) << 4;
    const int sl3 = c3 >> 1, sh3v = (c3 & 1) << 4;

    // ---------------- produce: 64 rows per wave ----------------
    float acc = 0.0f;
    const float* src = yp + ((size_t)b * 512 + h * 256 + w * 64) * 128 + lane * 2;
    v2f A8[8], B8[8];

#define ISSUE8(d_, p_)                                                         \
    asm volatile(                                                              \
        "global_load_dwordx2 %0, %8, off\n\t"                                  \
        "global_load_dwordx2 %1, %8, off offset:512\n\t"                       \
        "global_load_dwordx2 %2, %8, off offset:1024\n\t"                      \
        "global_load_dwordx2 %3, %8, off offset:1536\n\t"                      \
        "global_load_dwordx2 %4, %8, off offset:2048\n\t"                      \
        "global_load_dwordx2 %5, %8, off offset:2560\n\t"                      \
        "global_load_dwordx2 %6, %8, off offset:3072\n\t"                      \
        "global_load_dwordx2 %7, %8, off offset:3584"                          \
        : "=&v"(d_[0]), "=&v"(d_[1]), "=&v"(d_[2]), "=&v"(d_[3]),              \
          "=&v"(d_[4]), "=&v"(d_[5]), "=&v"(d_[6]), "=&v"(d_[7])               \
        : "v"(p_)                                                              \
        : "memory");

#define WAITN(n_)                                                              \
    {                                                                          \
        asm volatile("s_waitcnt vmcnt(" #n_ ")" ::: "memory");                 \
        __builtin_amdgcn_sched_barrier(0);                                     \
    }

#define PROC8(buf_, rb_)                                                       \
    {                                                                          \
        _Pragma("unroll")                                                      \
        for (int i = 0; i < 8; ++i) {                                          \
            const float vx = buf_[i].x, vy = buf_[i].y;                        \
            const float sall = rdl63(wave_sum63(__expf(vx) + __expf(vy)));     \
            const float xbv  = rdl63(vy);     /* blank = lane63.y */           \
            acc += __logf(sall) - xbv;                                         \
            const __half2 hh = __floats2half2_rn(vx, vy);                      \
            const int hb = __builtin_bit_cast(int, hh);                        \
            const int q1 = __shfl(hb, sl1, 64);                                \
            const int q3 = __shfl(hb, sl3, 64);                                \
            const float x1 = __half2float(__builtin_bit_cast(__half, (unsigned short)(q1 >> sh1v))); \
            const float x3 = __half2float(__builtin_bit_cast(__half, (unsigned short)(q3 >> sh3v))); \
            g[w * 64 + (rb_) + i][lane] =                                      \
                pk_bf16(__expf(x1 - xbv), __expf(x3 - xbv));                   \
        }                                                                      \
    }

    ISSUE8(A8, src)
    ISSUE8(B8, src + 8 * 128)
    WAITN(8)  PROC8(A8, 0)   ISSUE8(A8, src + 16 * 128)
    WAITN(8)  PROC8(B8, 8)   ISSUE8(B8, src + 24 * 128)
    WAITN(8)  PROC8(A8, 16)  ISSUE8(A8, src + 32 * 128)
    WAITN(8)  PROC8(B8, 24)  ISSUE8(B8, src + 40 * 128)
    WAITN(8)  PROC8(A8, 32)  ISSUE8(A8, src + 48 * 128)
    WAITN(8)  PROC8(B8, 40)  ISSUE8(B8, src + 56 * 128)
    WAITN(8)  PROC8(A8, 48)
    WAITN(0)  PROC8(B8, 56)

    if (lane == 0) accW[bh * 4 + w] = acc;
    __syncthreads();

    // ---------------- chain: wave 0 only ----------------
    if (w == 0) {
        const int cprev = __shfl_up(c3, 1, 64);
        const float sk1 = (lane > 0 && c1 != cprev) ? 1.0f : 0.0f;
        const float sk3 = (c3 != c1) ? 1.0f : 0.0f;
        const float skB3 = shl1(sk1, 0.0f);
        const int llen = __popcll(__ballot(c1 != 0)) + __popcll(__ballot(c3 != 0));

        float o0, o1, o2, o3, o4;
        int   Eacc = 0;
        int   er[8];

#define RENORM()                                                               \
    {                                                                          \
        float mr = fmaxf(fmaxf(fmaxf(o0, o1), fmaxf(o2, o3)), o4);             \
        const float mru = rdl63(wave_max63(mr));                               \
        const int ie = (__float_as_int(mru) >> 23) & 0xFF;                     \
        const float sc = __int_as_float((253 - ie) << 23);                     \
        o0 *= sc; o1 *= sc; o2 *= sc; o3 *= sc; o4 *= sc;                      \
        Eacc += ie - 126;                                                      \
    }

#define FSTEP(bits_, rn_)                                                      \
    {                                                                          \
        const float e1 = __int_as_float((bits_) << 16);                        \
        const float e3 = __int_as_float((bits_) & 0xFFFF0000);                 \
        const float pm = shr1(o3, 0.0f);                                       \
        const float n0 = o0 + pm;                                              \
        const float n1 = (o1 + o0 + sk1 * pm) * e1;                            \
        const float n2 = o2 + o1;                                              \
        const float n3 = (o3 + o2 + sk3 * o1) * e3;                            \
        o4 += o3;                                                              \
        o0 = n0; o1 = n1; o2 = n2; o3 = n3;                                    \
        if (rn_) RENORM();                                                     \
    }

#define BSTEP(bits_, rn_)                                                      \
    {                                                                          \
        const float e1 = __int_as_float((bits_) << 16);                        \
        const float e3 = __int_as_float((bits_) & 0xFFFF0000);                 \
        const float g1 = o1 * e1;                                              \
        const float g3 = o3 * e3;                                              \
        const float pm0 = shl1(o0, o4);      /* beta(4l+4); lane63 -> o4 */    \
        const float pm1 = shl1(g1, 0.0f);    /* gamma(4l+5); lane63 -> 0 */    \
        const float n0 = o0 + g1;                                              \
        const float n1 = g1 + o2 + sk3 * g3;                                   \
        const float n2 = o2 + g3;                                              \
        const float n3 = g3 + pm0 + skB3 * pm1;                                \
        o0 = n0; o1 = n1; o2 = n2; o3 = n3;                                    \
        if (rn_) RENORM();                                                     \
    }

        if (h == 0) {
            // forward: local rows 0..255 are global t = 0..255
            #pragma unroll
            for (int i = 0; i < 8; ++i) er[i] = g[i][lane];
            {
                const float e10 = __int_as_float(er[0] << 16);   // exp(d1) at t=0
                o0 = (lane == 0) ? 1.0f : 0.0f;
                o1 = (lane == 0) ? e10 : 0.0f;
                o2 = 0.0f; o3 = 0.0f; o4 = 0.0f;
            }
            er[0] = g[8][lane];
            #pragma unroll
            for (int t = 1; t < 8; ++t) { FSTEP(er[t], false); er[t] = g[t + 8][lane]; }
            #pragma unroll
            for (int tb = 8; tb < 248; tb += 8) {
                #pragma unroll
                for (int j = 0; j < 8; ++j) {
                    FSTEP(er[j], ((tb + j) & 31) == 0);
                    er[j] = g[tb + j + 8][lane];
                }
            }
            #pragma unroll
            for (int t = 248; t < 256; ++t) FSTEP(er[t & 7], false);
        } else {
            // backward: local rows 0..255 are global t = 256..511; walk down.
            #pragma unroll
            for (int i = 0; i < 8; ++i) er[i] = g[255 - i][lane];
            const int sA = 2 * llen, sB = 2 * llen - 1;   // readout states
            o0 = (4 * lane + 0 == sA) ? 1.0f : 0.0f;
            o1 = (4 * lane + 1 == sB) ? 1.0f : 0.0f;
            o2 = (4 * lane + 2 == sA) ? 1.0f : 0.0f;
            o3 = (4 * lane + 3 == sB) ? 1.0f : 0.0f;
            o4 = (llen == 128 && lane == 63) ? 1.0f : 0.0f;   // s = 256
            #pragma unroll
            for (int kb = 0; kb < 248; kb += 8) {
                #pragma unroll
                for (int j = 0; j < 8; ++j) {
                    const int r = 255 - (kb + j);
                    BSTEP(er[j], (r & 31) == 0);
                    er[j] = g[r - 8][lane];
                }
            }
            #pragma unroll
            for (int k = 248; k < 256; ++k) BSTEP(er[k & 7], ((255 - k) & 31) == 0);
        }

        // publish boundary vector (t = 255) + exponent
        float* Vh = V + (size_t)bh * VSTRIDE;
        Vh[4 * lane + 0] = o0; Vh[4 * lane + 1] = o1;
        Vh[4 * lane + 2] = o2; Vh[4 * lane + 3] = o3;
        if (lane == 63) Vh[256] = o4;
        if (lane == 0)  E[bh] = Eacc;
#undef BSTEP
#undef FSTEP
#undef RENORM
    }
#undef PROC8
#undef WAITN
#undef ISSUE8
}

// Combine: P = sum_s alphaF(s)*betaB(s) in DOUBLE (fp32 product of two
// max-normalized fields underflows when argmax states misalign).
__global__ __launch_bounds__(64) void combine(const float* __restrict__ V,
                                              const int* __restrict__ E,
                                              const float* __restrict__ accW,
                                              float* __restrict__ loss) {
    const int b = blockIdx.x, lane = threadIdx.x;
    const float* Vf = V + (size_t)(2 * b) * VSTRIDE;
    const float* Vb = Vf + VSTRIDE;
    const float4 a = *reinterpret_cast<const float4*>(Vf + 4 * lane);
    const float4 c = *reinterpret_cast<const float4*>(Vb + 4 * lane);
    double p = (double)a.x * (double)c.x + (double)a.y * (double)c.y
             + (double)a.z * (double)c.z + (double)a.w * (double)c.w;
    if (lane == 63) p += (double)Vf[256] * (double)Vb[256];
    #pragma unroll
    for (int off = 32; off > 0; off >>= 1) p += __shfl_xor(p, off, 64);
    if (lane == 0) {
        float ls = 0.0f;
        #pragma unroll
        for (int j = 0; j < 8; ++j) ls += accW[8 * b + j];
        const double lg = log(p) + (double)(E[2 * b] + E[2 * b + 1]) * LN2D - (double)ls;
        loss[b] = -(float)lg;
    }
}

// Deterministic mean over B=256 losses
__global__ __launch_bounds__(256) void finalize(const float* __restrict__ loss,
                                                float* __restrict__ out) {
    __shared__ float red[256];
    const int tid = threadIdx.x;
    red[tid] = loss[tid];
    __syncthreads();
    for (int off = 128; off > 0; off >>= 1) {
        if (tid < off) red[tid] += red[tid + off];
        __syncthreads();
    }
    if (tid == 0) out[0] = red[0] * (1.0f / 256.0f);
}

extern "C" void kernel_launch(void* const* d_in, const int* in_sizes, int n_in,
                              void* d_out, int out_size, void* d_ws, size_t ws_size,
                              hipStream_t stream) {
    constexpr int B = 256;
    const int*   y_true = (const int*)d_in[0];
    const float* y_pred = (const float*)d_in[1];
    float* out = (float*)d_out;

    float* V    = (float*)d_ws;                       // 512 * 260 floats
    int*   E    = (int*)(V + 512 * VSTRIDE);          // 512 ints
    float* accW = (float*)(E + 512);                  // 512 * 4 floats
    float* loss = accW + 2048;                        // 256 floats

    ctc_half<<<B * 2, 256, 0, stream>>>(y_true, y_pred, V, E, accW);
    combine<<<B, 64, 0, stream>>>(V, E, accW, loss);
    finalize<<<1, 256, 0, stream>>>(loss, out);
}